// Round 1
// baseline (204.035 us; speedup 1.0000x reference)
//
#include <hip/hip_runtime.h>
#include <cstdint>

#define N 8192
#define BLK 256
#define NBLOCKS 4096   // block b handles rows b and (N-2-b); combined length == N

// Vector-body partial of sum_{e in [0,L)} c2[O+e] * x[i+1+e].
// The 16B-aligned body (4*V elems starting at O+pro) reads x from a pre-shifted
// LDS copy via ds_read_b128; prolog (pro elems) and tail ((L-pro)&3 elems) read
// x straight from global (L1/L2-hot, <=3 elems each).
// Summation order is bit-identical to the previous kernel version.
__device__ __forceinline__ float row_partial_lds(const float* __restrict__ c2,
                                                 const float* __restrict__ x,
                                                 const float* xs_row,  // LDS, 16B-aligned
                                                 long long O, int L, int pro, int V, int i) {
    const int t = threadIdx.x;
    const float* cp = c2 + O;
    const float* xg = x + i + 1;
    float s = 0.0f;

    if (t < pro) s += cp[t] * xg[t];

    const float4* __restrict__ cv = (const float4*)(cp + pro);  // 16B-aligned coeff stream
    const float4* xv = (const float4*)xs_row;                   // 16B-aligned LDS x stream

    // Jam-2: two independent coeff dwordx4 loads in flight per wave.
    // Adds occur in the same ascending-v order as the original strided loop.
    int v = t;
    for (; v + BLK < V; v += 2 * BLK) {
        float4 ca = cv[v];
        float4 cb = cv[v + BLK];
        float4 xa = xv[v];
        float4 xb = xv[v + BLK];
        s += ca.x * xa.x + ca.y * xa.y + ca.z * xa.z + ca.w * xa.w;
        s += cb.x * xb.x + cb.y * xb.y + cb.z * xb.z + cb.w * xb.w;
    }
    if (v < V) {
        float4 c = cv[v];
        float4 xx = xv[v];
        s += c.x * xx.x + c.y * xx.y + c.z * xx.z + c.w * xx.w;
    }

    const int tail = (L - pro) & 3;
    if (t < tail) {
        const int e = (V << 2) + t;
        s += cp[pro + e] * xg[pro + e];
    }
    return s;
}

__global__ __launch_bounds__(BLK) void ham_main(const float* __restrict__ x,
                                                const float* __restrict__ coeffs,
                                                float* __restrict__ ws) {
    // 32 KB exactly: shifted x windows for both rows (vector bodies sum to <= 8192
    // floats since L1+L2 == N). Reused as the block-reduce scratch at the end.
    // 32 KB/block -> 5 blocks/CU (20 waves/CU).
    __shared__ __align__(16) float xs[N];

    const int b = blockIdx.x;
    const int t = threadIdx.x;
    const float* __restrict__ c1 = coeffs;
    const float* __restrict__ c2 = coeffs + N;

    // ---- row geometry ----
    const int i1 = b;
    const long long O1 = (long long)i1 * (2LL * N - i1 - 1) / 2;
    const int L1 = N - 1 - i1;                     // >= 4096, so pro1 never needs clamping
    const int pro1 = (int)((4 - (O1 & 3)) & 3);
    const int V1 = (L1 - pro1) >> 2;

    const int i2 = N - 2 - b;
    const bool has2 = (i2 > b);                    // middle row (b==4095) appears only once
    long long O2 = 0; int L2 = 0, pro2 = 0, V2 = 0;
    if (has2) {
        O2 = (long long)i2 * (2LL * N - i2 - 1) / 2;
        L2 = N - 1 - i2;                           // == b+1, can be tiny
        pro2 = (int)((4 - (O2 & 3)) & 3);
        if (pro2 > L2) pro2 = L2;
        V2 = (L2 - pro2) >> 2;
    }
    const int base2 = V1 << 2;                     // multiple of 4 floats -> 16B-aligned

    // ---- stage shifted x windows into LDS (vector bodies only) ----
    {
        const float* __restrict__ s1 = x + i1 + 1 + pro1;
        const int n1 = V1 << 2;
        for (int e = t; e < n1; e += BLK) xs[e] = s1[e];
        if (has2) {
            const float* __restrict__ s2 = x + i2 + 1 + pro2;
            float* d2 = xs + base2;
            const int n2 = V2 << 2;
            for (int e = t; e < n2; e += BLK) d2[e] = s2[e];
        }
    }
    __syncthreads();

    float acc = 0.0f;

    // Row i1 = b  (length N-1-b)
    acc += x[i1] * row_partial_lds(c2, x, xs, O1, L1, pro1, V1, i1);

    // Row i2 = N-2-b  (length b+1)
    if (has2) acc += x[i2] * row_partial_lds(c2, x, xs + base2, O2, L2, pro2, V2, i2);

    // Degree-1 terms: first 32 blocks cover 8192 elements
    {
        const int g = b * BLK + t;
        if (g < N) acc += c1[g] * x[g];
    }

    // Block reduction: wave shuffle (64-wide) then LDS across 4 waves (xs reused)
    #pragma unroll
    for (int o = 32; o > 0; o >>= 1) acc += __shfl_down(acc, o, 64);
    __syncthreads();                 // all xs reads done before scratch reuse
    const int wave = t >> 6;
    const int lane = t & 63;
    if (lane == 0) xs[wave] = acc;
    __syncthreads();
    if (t == 0) {
        float v = 0.0f;
        #pragma unroll
        for (int w = 0; w < BLK / 64; ++w) v += xs[w];
        ws[b] = v;   // unconditional write: d_ws is poisoned, never read-before-write
    }
}

__global__ __launch_bounds__(1024) void ham_reduce(const float* __restrict__ ws,
                                                   float* __restrict__ out) {
    const int t = threadIdx.x;
    float v = 0.0f;
    for (int idx = t; idx < NBLOCKS; idx += 1024) v += ws[idx];
    #pragma unroll
    for (int o = 32; o > 0; o >>= 1) v += __shfl_down(v, o, 64);
    __shared__ float smem[16];
    const int wave = t >> 6;
    const int lane = t & 63;
    if (lane == 0) smem[wave] = v;
    __syncthreads();
    if (t == 0) {
        float s = 0.0f;
        #pragma unroll
        for (int w = 0; w < 16; ++w) s += smem[w];
        out[0] = s;
    }
}

extern "C" void kernel_launch(void* const* d_in, const int* in_sizes, int n_in,
                              void* d_out, int out_size, void* d_ws, size_t ws_size,
                              hipStream_t stream) {
    const float* x      = (const float*)d_in[0];
    const float* coeffs = (const float*)d_in[1];
    float* out = (float*)d_out;
    float* ws  = (float*)d_ws;   // needs NBLOCKS*4 = 16 KB

    ham_main<<<NBLOCKS, BLK, 0, stream>>>(x, coeffs, ws);
    ham_reduce<<<1, 1024, 0, stream>>>(ws, out);
}

// Round 2
// 201.141 us; speedup vs baseline: 1.0144x; 1.0144x over previous
//
#include <hip/hip_runtime.h>
#include <cstdint>

#define N 8192
#define BLK 256
#define NBLOCKS 4096   // block b handles rows b and (N-2-b); combined length == N

// Vector body: sum_{v} c[4v..4v+3] . x[B+4v..B+4v+3], strided over the block,
// accumulating IN ORDER onto s0 (bit-identical add sequence to the round-0 kernel).
// Coeff stream is 16B-aligned (pro chosen for it). The x stream has per-row
// constant phase R = B&3; we load two aligned float4s and extract the 4
// contiguous values by compile-time register selection (zero ALU).
// The final quad (v == V-1) uses scalar x loads to avoid reading past x[N-1].
template <int R>
__device__ __forceinline__ float row_body(const float* __restrict__ cb,   // aligned coeff body
                                          const float* __restrict__ xA,   // x + (B & ~3), 16B-aligned
                                          const float* __restrict__ xB,   // x + B (body start, unaligned)
                                          int V, float s) {
    const int t = threadIdx.x;
    const float4* __restrict__ cv = (const float4*)cb;
    const float4* __restrict__ XA = (const float4*)xA;
    if (R == 0) {
        // Perfectly aligned: one dwordx4 for x, covers the body exactly.
        for (int v = t; v < V; v += BLK) {
            float4 c = cv[v];
            float4 xa = XA[v];
            s += c.x * xa.x + c.y * xa.y + c.z * xa.z + c.w * xa.w;
        }
    } else {
        for (int v = t; v < V; v += BLK) {
            float4 c = cv[v];
            float e0, e1, e2, e3;
            if (v + 1 < V) {                       // paired aligned loads, overlap L1-hot lines
                float4 xa = XA[v];
                float4 xb = XA[v + 1];
                if (R == 1)      { e0 = xa.y; e1 = xa.z; e2 = xa.w; e3 = xb.x; }
                else if (R == 2) { e0 = xa.z; e1 = xa.w; e2 = xb.x; e3 = xb.y; }
                else             { e0 = xa.w; e1 = xb.x; e2 = xb.y; e3 = xb.z; }
            } else {                               // last quad: scalar, stays in-bounds
                const float* xe = xB + (v << 2);
                e0 = xe[0]; e1 = xe[1]; e2 = xe[2]; e3 = xe[3];
            }
            s += c.x * e0 + c.y * e1 + c.z * e2 + c.w * e3;
        }
    }
    return s;
}

// Per-thread partial of sum_{e in [0,L)} c2[O+e] * x[i+1+e], block-strided.
// Identical summation order to the round-0 kernel (prolog, body ascending v, tail).
__device__ __forceinline__ float row_partial(const float* __restrict__ c2,
                                             const float* __restrict__ x,
                                             long long O, int L, int i) {
    const int t = threadIdx.x;
    const float* cp = c2 + O;
    const float* xg = x + i + 1;
    float s = 0.0f;

    int pro = (int)((4 - (O & 3)) & 3);   // scalar elems until coeff 16B alignment
    if (pro > L) pro = L;
    if (t < pro) s += cp[t] * xg[t];

    const int Rm = L - pro;
    const int V = Rm >> 2;                // # of float4's
    const int tail = Rm & 3;

    const float* cb = cp + pro;           // 16B-aligned coeff body
    const float* xB = xg + pro;           // x body start (phase r mod 4)
    const int Bidx = i + 1 + pro;
    const float* xA = x + (Bidx & ~3);    // aligned x base
    const int r = Bidx & 3;

    switch (r) {
        case 0:  s = row_body<0>(cb, xA, xB, V, s); break;
        case 1:  s = row_body<1>(cb, xA, xB, V, s); break;
        case 2:  s = row_body<2>(cb, xA, xB, V, s); break;
        default: s = row_body<3>(cb, xA, xB, V, s); break;
    }

    if (t < tail) {
        const int e = (V << 2) + t;
        s += cb[e] * xB[e];
    }
    return s;
}

__global__ __launch_bounds__(BLK) void ham_main(const float* __restrict__ x,
                                                const float* __restrict__ coeffs,
                                                float* __restrict__ ws) {
    const int b = blockIdx.x;
    const int t = threadIdx.x;
    const float* __restrict__ c1 = coeffs;
    const float* __restrict__ c2 = coeffs + N;

    float acc = 0.0f;

    // Row i1 = b  (length N-1-b)
    {
        const int i1 = b;
        const long long O1 = (long long)i1 * (2LL * N - i1 - 1) / 2;
        const int L1 = N - 1 - i1;
        const float s1 = row_partial(c2, x, O1, L1, i1);
        acc += x[i1] * s1;
    }
    // Row i2 = N-2-b  (length b+1); middle row (b==4095) appears only once
    {
        const int i2 = N - 2 - b;
        if (i2 > b) {
            const long long O2 = (long long)i2 * (2LL * N - i2 - 1) / 2;
            const int L2 = N - 1 - i2;
            const float s2 = row_partial(c2, x, O2, L2, i2);
            acc += x[i2] * s2;
        }
    }

    // Degree-1 terms: first 32 blocks cover 8192 elements
    {
        const int g = b * BLK + t;
        if (g < N) acc += c1[g] * x[g];
    }

    // Block reduction: wave shuffle (64-wide) then LDS across 4 waves
    #pragma unroll
    for (int o = 32; o > 0; o >>= 1) acc += __shfl_down(acc, o, 64);
    __shared__ float smem[BLK / 64];
    const int wave = t >> 6;
    const int lane = t & 63;
    if (lane == 0) smem[wave] = acc;
    __syncthreads();
    if (t == 0) {
        float v = 0.0f;
        #pragma unroll
        for (int w = 0; w < BLK / 64; ++w) v += smem[w];
        ws[b] = v;   // unconditional write: d_ws is poisoned, never read-before-write
    }
}

__global__ __launch_bounds__(1024) void ham_reduce(const float* __restrict__ ws,
                                                   float* __restrict__ out) {
    const int t = threadIdx.x;
    float v = 0.0f;
    for (int idx = t; idx < NBLOCKS; idx += 1024) v += ws[idx];
    #pragma unroll
    for (int o = 32; o > 0; o >>= 1) v += __shfl_down(v, o, 64);
    __shared__ float smem[16];
    const int wave = t >> 6;
    const int lane = t & 63;
    if (lane == 0) smem[wave] = v;
    __syncthreads();
    if (t == 0) {
        float s = 0.0f;
        #pragma unroll
        for (int w = 0; w < 16; ++w) s += smem[w];
        out[0] = s;
    }
}

extern "C" void kernel_launch(void* const* d_in, const int* in_sizes, int n_in,
                              void* d_out, int out_size, void* d_ws, size_t ws_size,
                              hipStream_t stream) {
    const float* x      = (const float*)d_in[0];
    const float* coeffs = (const float*)d_in[1];
    float* out = (float*)d_out;
    float* ws  = (float*)d_ws;   // needs NBLOCKS*4 = 16 KB

    ham_main<<<NBLOCKS, BLK, 0, stream>>>(x, coeffs, ws);
    ham_reduce<<<1, 1024, 0, stream>>>(ws, out);
}

// Round 3
// 194.254 us; speedup vs baseline: 1.0504x; 1.0355x over previous
//
#include <hip/hip_runtime.h>
#include <cstdint>

#define N 8192
#define BLK 256
#define NBLOCKS 4096   // block b handles rows b and (N-2-b); combined length == N

// Per-thread partial of sum_{e in [0,L)} c2[O+e] * x[i+1+e], strided over the block.
// float4-vectorized coeff stream with alignment prolog/tail (row offsets arbitrary mod 4).
// Body is jam-4: quads v, v+BLK, v+2BLK, v+3BLK per iteration -- all loads issued
// up front (4 coeff dwordx4 + 16 x dwords in flight), folded into s in the EXACT
// ascending-v order of the round-0 kernel (bit-identical summation).
__device__ __forceinline__ float row_partial(const float* __restrict__ c2,
                                             const float* __restrict__ x,
                                             long long O, int L, int i) {
    const int t = threadIdx.x;
    const float* cp = c2 + O;
    const float* xp = x + i + 1;
    float s = 0.0f;

    int pro = (int)((4 - (O & 3)) & 3);   // scalar elems until 16B alignment
    if (pro > L) pro = L;
    if (t < pro) s += cp[t] * xp[t];

    const int R = L - pro;
    const int V = R >> 2;      // # of float4's
    const int tail = R & 3;

    const float4* __restrict__ cv = (const float4*)(cp + pro);
    const float*  __restrict__ xv = xp + pro;

    int v = t;
    // jam-4 main body: 4 independent coeff lines + 16 x scalars in flight
    for (; v + 3 * BLK < V; v += 4 * BLK) {
        const float4 c0 = cv[v];
        const float4 c1 = cv[v +     BLK];
        const float4 c2q = cv[v + 2 * BLK];
        const float4 c3 = cv[v + 3 * BLK];
        const int e0 = v << 2;
        const int e1 = (v +     BLK) << 2;
        const int e2 = (v + 2 * BLK) << 2;
        const int e3 = (v + 3 * BLK) << 2;
        const float x00 = xv[e0], x01 = xv[e0 + 1], x02 = xv[e0 + 2], x03 = xv[e0 + 3];
        const float x10 = xv[e1], x11 = xv[e1 + 1], x12 = xv[e1 + 2], x13 = xv[e1 + 3];
        const float x20 = xv[e2], x21 = xv[e2 + 1], x22 = xv[e2 + 2], x23 = xv[e2 + 3];
        const float x30 = xv[e3], x31 = xv[e3 + 1], x32 = xv[e3 + 2], x33 = xv[e3 + 3];
        // fold in ascending-v order -- bit-identical to the jam-1 sequence
        s += c0.x * x00 + c0.y * x01 + c0.z * x02 + c0.w * x03;
        s += c1.x * x10 + c1.y * x11 + c1.z * x12 + c1.w * x13;
        s += c2q.x * x20 + c2q.y * x21 + c2q.z * x22 + c2q.w * x23;
        s += c3.x * x30 + c3.y * x31 + c3.z * x32 + c3.w * x33;
    }
    // residual: original jam-1 body, continues the same ascending-v order
    for (; v < V; v += BLK) {
        float4 c = cv[v];
        const int e = v << 2;
        s += c.x * xv[e] + c.y * xv[e + 1] + c.z * xv[e + 2] + c.w * xv[e + 3];
    }
    if (t < tail) {
        const int e = (V << 2) + t;
        s += cp[pro + e] * xv[e];
    }
    return s;
}

__global__ __launch_bounds__(BLK) void ham_main(const float* __restrict__ x,
                                                const float* __restrict__ coeffs,
                                                float* __restrict__ ws) {
    const int b = blockIdx.x;
    const int t = threadIdx.x;
    const float* __restrict__ c1 = coeffs;
    const float* __restrict__ c2 = coeffs + N;

    float acc = 0.0f;

    // Row i1 = b  (length N-1-b)
    {
        const int i1 = b;
        const long long O1 = (long long)i1 * (2LL * N - i1 - 1) / 2;
        const int L1 = N - 1 - i1;
        const float s1 = row_partial(c2, x, O1, L1, i1);
        acc += x[i1] * s1;
    }
    // Row i2 = N-2-b  (length b+1); middle row (b==4095) appears only once
    {
        const int i2 = N - 2 - b;
        if (i2 > b) {
            const long long O2 = (long long)i2 * (2LL * N - i2 - 1) / 2;
            const int L2 = N - 1 - i2;
            const float s2 = row_partial(c2, x, O2, L2, i2);
            acc += x[i2] * s2;
        }
    }

    // Degree-1 terms: first 32 blocks cover 8192 elements
    {
        const int g = b * BLK + t;
        if (g < N) acc += c1[g] * x[g];
    }

    // Block reduction: wave shuffle (64-wide) then LDS across 4 waves
    #pragma unroll
    for (int o = 32; o > 0; o >>= 1) acc += __shfl_down(acc, o, 64);
    __shared__ float smem[BLK / 64];
    const int wave = t >> 6;
    const int lane = t & 63;
    if (lane == 0) smem[wave] = acc;
    __syncthreads();
    if (t == 0) {
        float v = 0.0f;
        #pragma unroll
        for (int w = 0; w < BLK / 64; ++w) v += smem[w];
        ws[b] = v;   // unconditional write: d_ws is poisoned, never read-before-write
    }
}

__global__ __launch_bounds__(1024) void ham_reduce(const float* __restrict__ ws,
                                                   float* __restrict__ out) {
    const int t = threadIdx.x;
    float v = 0.0f;
    for (int idx = t; idx < NBLOCKS; idx += 1024) v += ws[idx];
    #pragma unroll
    for (int o = 32; o > 0; o >>= 1) v += __shfl_down(v, o, 64);
    __shared__ float smem[16];
    const int wave = t >> 6;
    const int lane = t & 63;
    if (lane == 0) smem[wave] = v;
    __syncthreads();
    if (t == 0) {
        float s = 0.0f;
        #pragma unroll
        for (int w = 0; w < 16; ++w) s += smem[w];
        out[0] = s;
    }
}

extern "C" void kernel_launch(void* const* d_in, const int* in_sizes, int n_in,
                              void* d_out, int out_size, void* d_ws, size_t ws_size,
                              hipStream_t stream) {
    const float* x      = (const float*)d_in[0];
    const float* coeffs = (const float*)d_in[1];
    float* out = (float*)d_out;
    float* ws  = (float*)d_ws;   // needs NBLOCKS*4 = 16 KB

    ham_main<<<NBLOCKS, BLK, 0, stream>>>(x, coeffs, ws);
    ham_reduce<<<1, 1024, 0, stream>>>(ws, out);
}